// Round 7
// baseline (162.011 us; speedup 1.0000x reference)
//
#include <hip/hip_runtime.h>
#include <math.h>

constexpr int B  = 32;
constexpr int C  = 9;
constexpr int NA = 65440;
constexpr int PER_B  = NA / 4;            // 16360 four-anchor groups per batch
constexpr int NTOT   = B * PER_B;         // 523520 work items
constexpr int BLOCK  = 256;
constexpr int GRID   = 512;               // 2 blocks/CU, ALL resident from t=0
constexpr int STRIDE = GRID * BLOCK;      // 131072 -> ~4 items/thread

// ws layout (floats): [0..511]=focal partials, [2048..]=reg, [4096..]=pos
constexpr int WS_REG = 2048;
constexpr int WS_POS = 4096;

typedef float f4 __attribute__((ext_vector_type(4)));
typedef int   i4 __attribute__((ext_vector_type(4)));

__device__ __forceinline__ f4 ldnt(const float* p) {
    return __builtin_nontemporal_load(reinterpret_cast<const f4*>(p));
}
__device__ __forceinline__ i4 ldnti(const int* p) {
    return __builtin_nontemporal_load(reinterpret_cast<const i4*>(p));
}
__device__ __forceinline__ f4 ld4(const float* p) {   // cached (anchors: 32x reuse)
    return *reinterpret_cast<const f4*>(p);
}
__device__ __forceinline__ float smooth_l1(float d) {
    float ad = fabsf(d);
    return ad < 1.0f ? 0.5f * d * d : ad - 0.5f;
}
// LDS slot swizzle for gt AoS->per-thread redistribution (bank-spread both ways).
__device__ __forceinline__ int swz(int i) { return i ^ ((i >> 3) & 7); }

__global__ __launch_bounds__(BLOCK, 2) void ssd_main(
    const float* __restrict__ bbox_delta,  // (B,4,NA)
    const float* __restrict__ confs,       // (B,C,NA)
    const float* __restrict__ gt_bbox,     // (B,NA,4)
    const int*   __restrict__ gt_labels,   // (B,NA)
    const float* __restrict__ anchors,     // (1,4,NA)
    float* __restrict__ ws)
{
    __shared__ f4 gswz[4][256];            // per-wave 4KB gt scratch, 16 KB total

    const int lane = threadIdx.x & 63;
    const int wid  = threadIdx.x >> 6;
    const f4* gt4  = reinterpret_cast<const f4*>(gt_bbox);   // f4 index == b*NA+a == 4*item

    float facc = 0.f, racc = 0.f, pacc = 0.f;

    // ---- prologue: conf-group(i0) ----
    int i = blockIdx.x * BLOCK + threadIdx.x;
    int b = i / PER_B;
    int a = (i - b * PER_B) * 4;
    f4 cf0, cf1, cf2, cf3, cf4, cf5, cf6, cf7, cf8; i4 lab;
    {
        const float* cb = confs + (size_t)b * C * NA + a;
        cf0 = ldnt(cb);          cf1 = ldnt(cb + 1 * NA); cf2 = ldnt(cb + 2 * NA);
        cf3 = ldnt(cb + 3 * NA); cf4 = ldnt(cb + 4 * NA); cf5 = ldnt(cb + 5 * NA);
        cf6 = ldnt(cb + 6 * NA); cf7 = ldnt(cb + 7 * NA); cf8 = ldnt(cb + 8 * NA);
        lab = ldnti(gt_labels + (size_t)b * NA + a);
    }
    __builtin_amdgcn_sched_barrier(0);

    f4 ncf0 = {0,0,0,0}, ncf1 = ncf0, ncf2 = ncf0, ncf3 = ncf0, ncf4 = ncf0,
       ncf5 = ncf0, ncf6 = ncf0, ncf7 = ncf0, ncf8 = ncf0;
    i4 nlab = {0,0,0,0};

    while (true) {
        // ---- issue reg-group(i): gv (dense gt slab) first, then delta, anchors ----
        const int iw = i - lane;                       // wave-uniform first item
        const size_t gb = (size_t)4 * iw;
        f4 gv0 = ldnt(reinterpret_cast<const float*>(gt4 + gb + 0 * 64 + lane));
        f4 gv1 = ldnt(reinterpret_cast<const float*>(gt4 + gb + 1 * 64 + lane));
        f4 gv2 = ldnt(reinterpret_cast<const float*>(gt4 + gb + 2 * 64 + lane));
        f4 gv3 = ldnt(reinterpret_cast<const float*>(gt4 + gb + 3 * 64 + lane));
        const float* db = bbox_delta + (size_t)b * 4 * NA + a;
        f4 d0 = ldnt(db);          f4 d1 = ldnt(db + NA);
        f4 d2 = ldnt(db + 2 * NA); f4 d3 = ldnt(db + 3 * NA);
        const float* ab = anchors + a;
        f4 ax = ld4(ab);          f4 ay = ld4(ab + NA);
        f4 aw = ld4(ab + 2 * NA); f4 ah = ld4(ab + 3 * NA);
        __builtin_amdgcn_sched_barrier(0);

        // ---- classification(i): waits only conf-group (vmcnt counted), reg-group flies
        {
            f4 cf[C] = {cf0, cf1, cf2, cf3, cf4, cf5, cf6, cf7, cf8};
            float sex = 0.f, sey = 0.f, sez = 0.f, sew = 0.f;
            float ctx = cf0[0], cty = cf0[1], ctz = cf0[2], ctw = cf0[3];
#pragma unroll
            for (int c = 0; c < C; ++c) {
                sex += __expf(cf[c][0]);
                sey += __expf(cf[c][1]);
                sez += __expf(cf[c][2]);
                sew += __expf(cf[c][3]);
                ctx = (lab[0] == c) ? cf[c][0] : ctx;
                cty = (lab[1] == c) ? cf[c][1] : cty;
                ctz = (lab[2] == c) ? cf[c][2] : ctz;
                ctw = (lab[3] == c) ? cf[c][3] : ctw;
            }
            float lpx = ctx - __logf(sex);
            float lpy = cty - __logf(sey);
            float lpz = ctz - __logf(sez);
            float lpw = ctw - __logf(sew);
            float px = __expf(lpx), py = __expf(lpy), pz = __expf(lpz), pw = __expf(lpw);
            float ox = 1.f - px, oy = 1.f - py, oz = 1.f - pz, ow = 1.f - pw;
            facc += ox*ox*ox*lpx + oy*oy*oy*lpy + oz*oz*oz*lpz + ow*ow*ow*lpw;
        }
        __builtin_amdgcn_sched_barrier(0);

        // ---- issue conf-group(i+1) (flies under gt-redistribute + regression) ----
        const int inext = i + STRIDE;
        const bool more = (inext < NTOT);              // wave- AND block-uniform
        int bn = 0, an = 0;
        if (more) {
            bn = inext / PER_B;
            an = (inext - bn * PER_B) * 4;
            const float* cbn = confs + (size_t)bn * C * NA + an;
            ncf0 = ldnt(cbn);          ncf1 = ldnt(cbn + 1 * NA); ncf2 = ldnt(cbn + 2 * NA);
            ncf3 = ldnt(cbn + 3 * NA); ncf4 = ldnt(cbn + 4 * NA); ncf5 = ldnt(cbn + 5 * NA);
            ncf6 = ldnt(cbn + 6 * NA); ncf7 = ldnt(cbn + 7 * NA); ncf8 = ldnt(cbn + 8 * NA);
            nlab = ldnti(gt_labels + (size_t)bn * NA + an);
        }
        __builtin_amdgcn_sched_barrier(0);

        // ---- gt redistribution through swizzled LDS (wave-local, no barrier) ----
        gswz[wid][swz(0 * 64 + lane)] = gv0;
        gswz[wid][swz(1 * 64 + lane)] = gv1;
        gswz[wid][swz(2 * 64 + lane)] = gv2;
        gswz[wid][swz(3 * 64 + lane)] = gv3;
        const int i0 = lane << 2;
        f4 g0 = gswz[wid][swz(i0 + 0)];
        f4 g1 = gswz[wid][swz(i0 + 1)];
        f4 g2 = gswz[wid][swz(i0 + 2)];
        f4 g3 = gswz[wid][swz(i0 + 3)];

        // ---- regression(i) ----
#define DO_ANCHOR(K)                                                              \
        {                                                                         \
            float gx = 10.0f * __fdividef(g##K[0] - ax[K], aw[K]);                \
            float gy = 10.0f * __fdividef(g##K[1] - ay[K], ah[K]);                \
            float gw = 5.0f * __logf(__fdividef(g##K[2], aw[K]));                 \
            float gh = 5.0f * __logf(__fdividef(g##K[3], ah[K]));                 \
            float s  = smooth_l1(d0[K] - gx) + smooth_l1(d1[K] - gy) +            \
                       smooth_l1(d2[K] - gw) + smooth_l1(d3[K] - gh);             \
            if (lab[K] > 0) { racc += s; pacc += 1.0f; }                          \
        }
        DO_ANCHOR(0)
        DO_ANCHOR(1)
        DO_ANCHOR(2)
        DO_ANCHOR(3)
#undef DO_ANCHOR

        if (!more) break;
        i = inext; b = bn; a = an;
        cf0 = ncf0; cf1 = ncf1; cf2 = ncf2; cf3 = ncf3; cf4 = ncf4;
        cf5 = ncf5; cf6 = ncf6; cf7 = ncf7; cf8 = ncf8; lab = nlab;
    }

    // ---- reduction: wave64 shuffle -> LDS -> one partial-write per block ----
#pragma unroll
    for (int off = 32; off > 0; off >>= 1) {
        facc += __shfl_down(facc, off, 64);
        racc += __shfl_down(racc, off, 64);
        pacc += __shfl_down(pacc, off, 64);
    }
    __shared__ float sf[4], sr[4], sp[4];
    if (lane == 0) { sf[wid] = facc; sr[wid] = racc; sp[wid] = pacc; }
    __syncthreads();
    if (threadIdx.x == 0) {
        ws[blockIdx.x]          = sf[0] + sf[1] + sf[2] + sf[3];
        ws[WS_REG + blockIdx.x] = sr[0] + sr[1] + sr[2] + sr[3];
        ws[WS_POS + blockIdx.x] = sp[0] + sp[1] + sp[2] + sp[3];
    }
}

__global__ __launch_bounds__(256) void finalize_k(const float* __restrict__ ws,
                                                  float* __restrict__ out) {
    float F = 0.f, R = 0.f, P = 0.f;
    for (int i = threadIdx.x; i < GRID; i += 256) {
        F += ws[i];
        R += ws[WS_REG + i];
        P += ws[WS_POS + i];
    }
#pragma unroll
    for (int off = 32; off > 0; off >>= 1) {
        F += __shfl_down(F, off, 64);
        R += __shfl_down(R, off, 64);
        P += __shfl_down(P, off, 64);
    }
    __shared__ float sf[4], sr[4], sp[4];
    const int wid  = threadIdx.x >> 6;
    const int lane = threadIdx.x & 63;
    if (lane == 0) { sf[wid] = F; sr[wid] = R; sp[wid] = P; }
    __syncthreads();
    if (threadIdx.x == 0) {
        float Ft = sf[0] + sf[1] + sf[2] + sf[3];
        float Rt = sr[0] + sr[1] + sr[2] + sr[3];
        float Pt = sp[0] + sp[1] + sp[2] + sp[3];
        // sum(alpha) = 10 + 8*1000 = 8010 ; classification = mean(-8010 * focal)
        const float inv_n = 1.0f / (float)((size_t)B * NA);
        out[0] = Rt / Pt - 8010.0f * Ft * inv_n;
    }
}

extern "C" void kernel_launch(void* const* d_in, const int* in_sizes, int n_in,
                              void* d_out, int out_size, void* d_ws, size_t ws_size,
                              hipStream_t stream) {
    const float* bbox_delta = (const float*)d_in[0];
    const float* confs      = (const float*)d_in[1];
    const float* gt_bbox    = (const float*)d_in[2];
    const int*   gt_labels  = (const int*)d_in[3];
    const float* anchors    = (const float*)d_in[4];
    float* ws  = (float*)d_ws;
    float* out = (float*)d_out;

    ssd_main<<<GRID, BLOCK, 0, stream>>>(bbox_delta, confs, gt_bbox, gt_labels, anchors, ws);
    finalize_k<<<1, 256, 0, stream>>>(ws, out);
}